// Round 6
// baseline (65.473 us; speedup 1.0000x reference)
//
#include <hip/hip_runtime.h>
#include <math.h>

// Problem constants (from setup_inputs): B=4, C=4, H=96, W=96
#define BB 4
#define CC 4
#define HH 96
#define WW 96
#define NN (HH * WW)
#define WPR (WW / 4)          // 24 u32 words per row
#define NW (NN / 4)           // 2304 words per image
#define BIGF 1e10f
#define QROWS (HH / 4)        // 24 rows per block quarter
// Harness guarantee: d_ws is re-poisoned to 0xAA bytes before EVERY timed
// launch, so u32 words in d_ws start at exactly 0xAAAAAAAA each call.
#define POISON_U32 0xAAAAAAAAu

// ---------------------------------------------------------------------------
// Single (ordinary) kernel. One block per (batch b, direction e, quarter q),
// blk = b*8 + e*4 + q.
//   e=0: EDT of maskP, masked max over maskT pixels (bwd)
//   e=1: EDT of maskT, masked max over maskP pixels (fwd)
// Tail: per-batch device-scope atomicMax of the clamped (>=0) squared max,
// then last-arrival finalize via an atomic counter (initial value = poison).
// Cooperative launch measured +23 µs (R4); second dispatch measured ~2-4 µs
// (R5) — this removes both.
// ---------------------------------------------------------------------------
__global__ __launch_bounds__(1024) void k_all(const float* __restrict__ out,
                                              const int* __restrict__ tgt,
                                              unsigned int* __restrict__ ws,
                                              float* __restrict__ outv) {
    // ws[0..3] = acc[b] (float bits, via atomicMax on int; values >= 0)
    // ws[4]    = arrival counter (starts at POISON_U32)
    // LDS carve, 64,512 B total. Region A (36864 B) is time-shared:
    //   P1/P2: predL (9216) + tgtL (9216);  P3b/P4: gq (full 36864, fp32 EDT)
    __shared__ __align__(16) unsigned char smem[64512];
    unsigned char* predL  = smem;                          //  9216 B (dead after P2)
    unsigned char* tgtL   = smem + 9216;                   //  9216 B (dead after P2)
    float* gq             = (float*)smem;                  // 36864 B (live from P3b)
    unsigned char* maskE  = smem + 36864;                  //  9216 B
    unsigned char* maskO  = smem + 46080;                  //  9216 B
    unsigned int* colbits = (unsigned int*)(smem + 55296); //  1920 B (stride 5)
    float* red            = (float*)(smem + 57216);        //    64 B

    const int blk = blockIdx.x;
    const int q = blk & 3;
    const int e = (blk >> 2) & 1;
    const int b = blk >> 3;
    const int tid = threadIdx.x;

    // ---- P1: argmax over C (strict >, first-max) + pack tgt to u8. 4 px/thread ----
    const float* obase = out + (size_t)b * CC * NN;
    const int* tbase = tgt + b * NN;
    for (int w = tid; w < NW; w += 1024) {
        int p = w * 4;
        float4 c0 = *(const float4*)(obase + p);
        float4 c1 = *(const float4*)(obase + NN + p);
        float4 c2 = *(const float4*)(obase + 2 * NN + p);
        float4 c3 = *(const float4*)(obase + 3 * NN + p);
        unsigned int pk = 0;
        {
            float bv = c0.x; int bc = 0;
            if (c1.x > bv) { bv = c1.x; bc = 1; }
            if (c2.x > bv) { bv = c2.x; bc = 2; }
            if (c3.x > bv) { bv = c3.x; bc = 3; }
            pk |= (unsigned int)bc;
        }
        {
            float bv = c0.y; int bc = 0;
            if (c1.y > bv) { bv = c1.y; bc = 1; }
            if (c2.y > bv) { bv = c2.y; bc = 2; }
            if (c3.y > bv) { bv = c3.y; bc = 3; }
            pk |= (unsigned int)bc << 8;
        }
        {
            float bv = c0.z; int bc = 0;
            if (c1.z > bv) { bv = c1.z; bc = 1; }
            if (c2.z > bv) { bv = c2.z; bc = 2; }
            if (c3.z > bv) { bv = c3.z; bc = 3; }
            pk |= (unsigned int)bc << 16;
        }
        {
            float bv = c0.w; int bc = 0;
            if (c1.w > bv) { bv = c1.w; bc = 1; }
            if (c2.w > bv) { bv = c2.w; bc = 2; }
            if (c3.w > bv) { bv = c3.w; bc = 3; }
            pk |= (unsigned int)bc << 24;
        }
        ((unsigned int*)predL)[w] = pk;
        int4 tv = *(const int4*)(tbase + p);
        ((unsigned int*)tgtL)[w] =
            (tv.x & 0xFF) | ((tv.y & 0xFF) << 8) | ((tv.z & 0xFF) << 16) | ((tv.w & 0xFF) << 24);
    }
    __syncthreads();

    // ---- P2: boundary masks, word-parallel (4 px/thread) ----
    const unsigned int* pw = (const unsigned int*)predL;
    const unsigned int* tw = (const unsigned int*)tgtL;
    for (int w = tid; w < NW; w += 1024) {
        int i = w / WPR;
        int jw = w - i * WPR;
        unsigned int mP, mT;
        #pragma unroll
        for (int s = 0; s < 2; ++s) {
            const unsigned int* src = s ? tw : pw;
            unsigned int c = src[w];
            unsigned int diff = 0;
            if (i > 0)      diff |= c ^ src[w - WPR];
            if (i < HH - 1) diff |= c ^ src[w + WPR];
            unsigned int l = (c << 8) | (jw > 0 ? (src[w - 1] >> 24) : (c & 0xFFu));
            diff |= c ^ l;
            unsigned int r = (c >> 8) | (jw < WPR - 1 ? (src[w + 1] << 24) : (c & 0xFF000000u));
            diff |= c ^ r;
            // per-byte nonzero -> 0x01
            unsigned int y = (((diff & 0x7F7F7F7Fu) + 0x7F7F7F7Fu) | diff) & 0x80808080u;
            unsigned int m01 = (y >> 7);
            if (s) mT = m01; else mP = m01;
        }
        ((unsigned int*)maskE)[w] = e ? mT : mP;
        ((unsigned int*)maskO)[w] = e ? mP : mT;
    }
    __syncthreads();   // maskE/maskO ready; predL/tgtL dead from here

    // ---- P3a: pack columns of maskE into bitmasks (3 u32 words / column) ----
    if (tid < 96 * 3) {
        int j = tid / 3, w = tid - j * 3;
        const unsigned char* colp = &maskE[w * 32 * WW + j];
        unsigned int bits = 0;
        #pragma unroll
        for (int r = 0; r < 32; ++r) bits |= ((unsigned int)colp[r * WW]) << r;
        colbits[j * 5 + w] = bits;
    }
    __syncthreads();

    // ---- P3b: column EDT, O(1)/pixel via clz/ffs on the column bitmask ----
    for (int p = tid; p < NN; p += 1024) {
        int i = p / WW;
        int j = p - i * WW;
        unsigned int w0 = colbits[j * 5 + 0];
        unsigned int w1 = colbits[j * 5 + 1];
        unsigned int hi = colbits[j * 5 + 2];
        unsigned long long lo = (unsigned long long)w0 | ((unsigned long long)w1 << 32);
        int up = 1 << 20, dn = 1 << 20;
        if (i < 64) {
            unsigned long long mu = lo & (~0ull >> (63 - i));          // rows 0..i
            if (mu) up = i - (63 - __clzll(mu));
            unsigned long long md = lo >> i;                           // rows i..63
            if (md) dn = __ffsll(md) - 1;
            else if (hi) dn = (64 - i) + (__ffs(hi) - 1);
        } else {
            int ih = i - 64;
            unsigned int mu = hi & (0xFFFFFFFFu >> (31 - ih));         // rows 64..i
            if (mu) up = ih - (31 - __clz(mu));
            else if (lo) up = i - (63 - __clzll(lo));
            unsigned int md = hi >> ih;                                // rows i..95
            if (md) dn = __ffs(md) - 1;
        }
        int d = (up < dn) ? up : dn;
        gq[p] = (d < HH) ? (float)(d * d) : BIGF;
    }
    __syncthreads();

    // ---- P4: row pass (exact sq. EDT) fused with masked max over maskO ----
    float m = -BIGF;
    const int pix0 = q * QROWS * WW;          // this block's 2304 pixels
    for (int p4 = tid; p4 < QROWS * WW; p4 += 1024) {
        int p = pix0 + p4;
        int i = p / WW;
        int j = p - i * WW;
        const float* grow = &gq[i * WW];
        float best = BIGF;
        float d0 = (float)j;                   // j - jp, jp starts at 0
        #pragma unroll 6
        for (int jp = 0; jp < WW; jp += 4) {
            float4 gv = *(const float4*)(grow + jp);   // wave-uniform addr: broadcast
            float a0 = d0;        best = fminf(best, fmaf(a0, a0, gv.x));
            float a1 = d0 - 1.f;  best = fminf(best, fmaf(a1, a1, gv.y));
            float a2 = d0 - 2.f;  best = fminf(best, fmaf(a2, a2, gv.z));
            float a3 = d0 - 3.f;  best = fminf(best, fmaf(a3, a3, gv.w));
            d0 -= 4.0f;
        }
        if (maskO[p]) m = fmaxf(m, best);
    }
    // block max-reduce (16 waves)
    #pragma unroll
    for (int off = 32; off > 0; off >>= 1) m = fmaxf(m, __shfl_down(m, off));
    const int wid = tid >> 6, lid = tid & 63;
    if (lid == 0) red[wid] = m;
    __syncthreads();

    // ---- tail: device-scope fold + last-arrival finalize (single dispatch) ----
    if (tid == 0) {
        float mm = red[0];
        #pragma unroll
        for (int w = 1; w < 16; ++w) mm = fmaxf(mm, red[w]);
        // clamp >= 0 (matches reference's max(...,0) before sqrt); makes
        // signed-int atomicMax order-correct on float bits.
        mm = fmaxf(mm, 0.0f);
        atomicMax((int*)&ws[b], __float_as_int(mm));
        __threadfence();                               // acc visible device-wide
        unsigned int old = atomicAdd(&ws[4], 1u);
        if (old == POISON_U32 + 31u) {                 // last of 32 blocks
            __threadfence();
            float s = 0.0f;
            #pragma unroll
            for (int bb = 0; bb < BB; ++bb) {
                // device-scope atomic read of acc[bb]
                unsigned int bits = atomicAdd(&ws[bb], 0u);
                s += sqrtf(__int_as_float((int)bits));
            }
            outv[0] = s * 0.25f;
        }
    }
}

// ---------------------------------------------------------------------------
extern "C" void kernel_launch(void* const* d_in, const int* in_sizes, int n_in,
                              void* d_out, int out_size, void* d_ws, size_t ws_size,
                              hipStream_t stream) {
    const float* output = (const float*)d_in[0];   // [B,C,H,W] fp32
    const int* target   = (const int*)d_in[1];     // [B,H,W] int32
    float* outv         = (float*)d_out;           // scalar fp32
    unsigned int* ws    = (unsigned int*)d_ws;     // acc[4] + counter

    k_all<<<32, 1024, 0, stream>>>(output, target, ws, outv);
}

// Round 7
// 61.471 us; speedup vs baseline: 1.0651x; 1.0651x over previous
//
#include <hip/hip_runtime.h>
#include <math.h>

// Problem constants (from setup_inputs): B=4, C=4, H=96, W=96
#define BB 4
#define CC 4
#define HH 96
#define WW 96
#define NN (HH * WW)
#define WPR (WW / 4)          // 24 u32 words per row
#define NW (NN / 4)           // 2304 words per image
#define BIGF 1e10f
#define QROWS (HH / 4)        // 24 rows per block quarter

// ---------------------------------------------------------------------------
// K1: one block per (batch b, direction e, quarter q). blk = b*8 + e*4 + q
//   e=0: EDT of maskP, masked max over maskT pixels (bwd)
//   e=1: EDT of maskT, masked max over maskP pixels (fwd)
// All intermediates in LDS. Vectorized prep, bitmask column EDT (clz/ffs),
// EARLY-EXIT row pass (exact: stop once o^2 >= best). Two ordinary
// dispatches — cooperative launch cost +23 µs (R4); in-kernel atomic
// finalize was neutral-to-worse (R6).
// ---------------------------------------------------------------------------
__global__ __launch_bounds__(1024) void k_fused(const float* __restrict__ out,
                                                const int* __restrict__ tgt,
                                                float* __restrict__ partial) {
    // LDS carve, 64,512 B total. Region A (36864 B) is time-shared:
    //   P1/P2: predL (9216) + tgtL (9216);  P3b/P4: gq (36864, fp32 EDT)
    __shared__ __align__(16) unsigned char smem[64512];
    unsigned char* predL  = smem;                          //  9216 B (dead after P2)
    unsigned char* tgtL   = smem + 9216;                   //  9216 B (dead after P2)
    float* gq             = (float*)smem;                  // 36864 B (live from P3b)
    unsigned char* maskE  = smem + 36864;                  //  9216 B
    unsigned char* maskO  = smem + 46080;                  //  9216 B
    unsigned int* colbits = (unsigned int*)(smem + 55296); //  1920 B (stride 5)
    float* red            = (float*)(smem + 57216);        //    64 B

    const int blk = blockIdx.x;
    const int q = blk & 3;
    const int e = (blk >> 2) & 1;
    const int b = blk >> 3;
    const int tid = threadIdx.x;

    // ---- P1: argmax over C (strict >, first-max) + pack tgt to u8. 4 px/thread ----
    const float* obase = out + (size_t)b * CC * NN;
    const int* tbase = tgt + b * NN;
    for (int w = tid; w < NW; w += 1024) {
        int p = w * 4;
        float4 c0 = *(const float4*)(obase + p);
        float4 c1 = *(const float4*)(obase + NN + p);
        float4 c2 = *(const float4*)(obase + 2 * NN + p);
        float4 c3 = *(const float4*)(obase + 3 * NN + p);
        unsigned int pk = 0;
        {
            float bv = c0.x; int bc = 0;
            if (c1.x > bv) { bv = c1.x; bc = 1; }
            if (c2.x > bv) { bv = c2.x; bc = 2; }
            if (c3.x > bv) { bv = c3.x; bc = 3; }
            pk |= (unsigned int)bc;
        }
        {
            float bv = c0.y; int bc = 0;
            if (c1.y > bv) { bv = c1.y; bc = 1; }
            if (c2.y > bv) { bv = c2.y; bc = 2; }
            if (c3.y > bv) { bv = c3.y; bc = 3; }
            pk |= (unsigned int)bc << 8;
        }
        {
            float bv = c0.z; int bc = 0;
            if (c1.z > bv) { bv = c1.z; bc = 1; }
            if (c2.z > bv) { bv = c2.z; bc = 2; }
            if (c3.z > bv) { bv = c3.z; bc = 3; }
            pk |= (unsigned int)bc << 16;
        }
        {
            float bv = c0.w; int bc = 0;
            if (c1.w > bv) { bv = c1.w; bc = 1; }
            if (c2.w > bv) { bv = c2.w; bc = 2; }
            if (c3.w > bv) { bv = c3.w; bc = 3; }
            pk |= (unsigned int)bc << 24;
        }
        ((unsigned int*)predL)[w] = pk;
        int4 tv = *(const int4*)(tbase + p);
        ((unsigned int*)tgtL)[w] =
            (tv.x & 0xFF) | ((tv.y & 0xFF) << 8) | ((tv.z & 0xFF) << 16) | ((tv.w & 0xFF) << 24);
    }
    __syncthreads();

    // ---- P2: boundary masks, word-parallel (4 px/thread) ----
    const unsigned int* pw = (const unsigned int*)predL;
    const unsigned int* tw = (const unsigned int*)tgtL;
    for (int w = tid; w < NW; w += 1024) {
        int i = w / WPR;
        int jw = w - i * WPR;
        unsigned int mP, mT;
        #pragma unroll
        for (int s = 0; s < 2; ++s) {
            const unsigned int* src = s ? tw : pw;
            unsigned int c = src[w];
            unsigned int diff = 0;
            if (i > 0)      diff |= c ^ src[w - WPR];
            if (i < HH - 1) diff |= c ^ src[w + WPR];
            unsigned int l = (c << 8) | (jw > 0 ? (src[w - 1] >> 24) : (c & 0xFFu));
            diff |= c ^ l;
            unsigned int r = (c >> 8) | (jw < WPR - 1 ? (src[w + 1] << 24) : (c & 0xFF000000u));
            diff |= c ^ r;
            // per-byte nonzero -> 0x01
            unsigned int y = (((diff & 0x7F7F7F7Fu) + 0x7F7F7F7Fu) | diff) & 0x80808080u;
            unsigned int m01 = (y >> 7);
            if (s) mT = m01; else mP = m01;
        }
        ((unsigned int*)maskE)[w] = e ? mT : mP;
        ((unsigned int*)maskO)[w] = e ? mP : mT;
    }
    __syncthreads();   // maskE/maskO ready; predL/tgtL dead from here

    // ---- P3a: pack columns of maskE into bitmasks (3 u32 words / column) ----
    if (tid < 96 * 3) {
        int j = tid / 3, w = tid - j * 3;
        const unsigned char* colp = &maskE[w * 32 * WW + j];
        unsigned int bits = 0;
        #pragma unroll
        for (int r = 0; r < 32; ++r) bits |= ((unsigned int)colp[r * WW]) << r;
        colbits[j * 5 + w] = bits;
    }
    __syncthreads();

    // ---- P3b: column EDT via clz/ffs — ONLY this block's quarter rows ----
    const int pix0 = q * QROWS * WW;          // this block's 2304 pixels
    for (int p4 = tid; p4 < QROWS * WW; p4 += 1024) {
        int p = pix0 + p4;
        int i = p / WW;
        int j = p - i * WW;
        unsigned int w0 = colbits[j * 5 + 0];
        unsigned int w1 = colbits[j * 5 + 1];
        unsigned int hi = colbits[j * 5 + 2];
        unsigned long long lo = (unsigned long long)w0 | ((unsigned long long)w1 << 32);
        int up = 1 << 20, dn = 1 << 20;
        if (i < 64) {
            unsigned long long mu = lo & (~0ull >> (63 - i));          // rows 0..i
            if (mu) up = i - (63 - __clzll(mu));
            unsigned long long md = lo >> i;                           // rows i..63
            if (md) dn = __ffsll(md) - 1;
            else if (hi) dn = (64 - i) + (__ffs(hi) - 1);
        } else {
            int ih = i - 64;
            unsigned int mu = hi & (0xFFFFFFFFu >> (31 - ih));         // rows 64..i
            if (mu) up = ih - (31 - __clz(mu));
            else if (lo) up = i - (63 - __clzll(lo));
            unsigned int md = hi >> ih;                                // rows i..95
            if (md) dn = __ffs(md) - 1;
        }
        int d = (up < dn) ? up : dn;
        gq[p] = (d < HH) ? (float)(d * d) : BIGF;
    }
    __syncthreads();

    // ---- P4: row pass, EXACT early-exit outward scan + masked max ----
    // best = min over o of g[j +- o] + o^2; stop once o^2 >= best (all
    // farther columns contribute >= o^2). Dense masks -> ~1-2 offsets.
    float m = -BIGF;
    for (int p4 = tid; p4 < QROWS * WW; p4 += 1024) {
        int p = pix0 + p4;
        int i = p / WW;
        int j = p - i * WW;
        const float* grow = &gq[i * WW];
        float best = grow[j];
        for (int o = 1; o < WW; ++o) {
            float o2 = (float)(o * o);
            if (o2 >= best) break;
            int jl = j - o, jr = j + o;
            if (jl >= 0)  best = fminf(best, grow[jl] + o2);
            if (jr < WW)  best = fminf(best, grow[jr] + o2);
        }
        if (maskO[p]) m = fmaxf(m, best);
    }
    // block max-reduce (16 waves)
    #pragma unroll
    for (int off = 32; off > 0; off >>= 1) m = fmaxf(m, __shfl_down(m, off));
    const int wid = tid >> 6, lid = tid & 63;
    if (lid == 0) red[wid] = m;
    __syncthreads();
    if (tid == 0) {
        float mm = red[0];
        #pragma unroll
        for (int w = 1; w < 16; ++w) mm = fmaxf(mm, red[w]);
        partial[blk] = mm;
    }
}

// ---------------------------------------------------------------------------
// K2: combine 32 partials -> mean over batches of sqrt(max(fwd,bwd,0))
// ---------------------------------------------------------------------------
__global__ void k_fin(const float* __restrict__ partial, float* __restrict__ outv) {
    if (threadIdx.x == 0) {
        float s = 0.0f;
        #pragma unroll
        for (int b = 0; b < BB; ++b) {
            float bwd = -BIGF, fwd = -BIGF;
            #pragma unroll
            for (int qq = 0; qq < 4; ++qq) {
                bwd = fmaxf(bwd, partial[b * 8 + qq]);       // e=0 quarters
                fwd = fmaxf(fwd, partial[b * 8 + 4 + qq]);   // e=1 quarters
            }
            s += sqrtf(fmaxf(fmaxf(fwd, bwd), 0.0f));
        }
        outv[0] = s * 0.25f;
    }
}

// ---------------------------------------------------------------------------
extern "C" void kernel_launch(void* const* d_in, const int* in_sizes, int n_in,
                              void* d_out, int out_size, void* d_ws, size_t ws_size,
                              hipStream_t stream) {
    const float* output = (const float*)d_in[0];   // [B,C,H,W] fp32
    const int* target   = (const int*)d_in[1];     // [B,H,W] int32
    float* outv         = (float*)d_out;           // scalar fp32
    float* partial      = (float*)d_ws;            // 32 floats

    k_fused<<<32, 1024, 0, stream>>>(output, target, partial);
    k_fin<<<1, 64, 0, stream>>>(partial, outv);
}

// Round 8
// 61.353 us; speedup vs baseline: 1.0671x; 1.0019x over previous
//
#include <hip/hip_runtime.h>
#include <math.h>

// Problem constants (from setup_inputs): B=4, C=4, H=96, W=96
#define BB 4
#define CC 4
#define HH 96
#define WW 96
#define NN (HH * WW)
#define WPR (WW / 4)          // 24 u32 words per row
#define NW (NN / 4)           // 2304 words per image
#define BIGF 1e10f
#define OROWS (HH / 8)        // 12 rows per block octant

// ---------------------------------------------------------------------------
// K1: one block per (batch b, direction e, octant o). blk = b*16 + e*8 + o
//   e=0: EDT of maskP, masked max over maskT pixels (bwd)
//   e=1: EDT of maskT, masked max over maskP pixels (fwd)
// All intermediates in LDS. Pipelined vectorized prep, bitmask column EDT
// (clz/ffs, own rows only), early-exit row pass gated on maskO.
// History: cooperative launch +23 µs (R4); in-kernel atomic finalize
// neutral-to-worse (R6); early-exit P4 −4 µs (R7).
// ---------------------------------------------------------------------------
__global__ __launch_bounds__(1024) void k_fused(const float* __restrict__ out,
                                                const int* __restrict__ tgt,
                                                float* __restrict__ partial) {
    // LDS carve, 64,512 B total. Region A (36864 B) is time-shared:
    //   P1/P2: predL (9216) + tgtL (9216);  P3b/P4: gq (36864, fp32 EDT)
    __shared__ __align__(16) unsigned char smem[64512];
    unsigned char* predL  = smem;                          //  9216 B (dead after P2)
    unsigned char* tgtL   = smem + 9216;                   //  9216 B (dead after P2)
    float* gq             = (float*)smem;                  // 36864 B (live from P3b)
    unsigned char* maskE  = smem + 36864;                  //  9216 B
    unsigned char* maskO  = smem + 46080;                  //  9216 B
    unsigned int* colbits = (unsigned int*)(smem + 55296); //  1920 B (stride 5)
    float* red            = (float*)(smem + 57216);        //    64 B

    const int blk = blockIdx.x;
    const int oct = blk & 7;
    const int e = (blk >> 3) & 1;
    const int b = blk >> 4;
    const int tid = threadIdx.x;

    // ---- P1: argmax over C (strict >, first-max) + pack tgt to u8 ----
    // Manually pipelined: all global loads issued before any LDS write.
    // NW = 2304 = 2*1024 + 256: every thread does w0,w1; tid<256 also w2.
    const float* obase = out + (size_t)b * CC * NN;
    const int* tbase = tgt + b * NN;
    {
        const int w0 = tid, w1 = tid + 1024, w2 = tid + 2048;
        const bool has2 = (tid < NW - 2048);
        const int p0 = w0 * 4, p1 = w1 * 4, p2 = has2 ? w2 * 4 : 0;

        float4 a0 = *(const float4*)(obase + p0);
        float4 a1 = *(const float4*)(obase + NN + p0);
        float4 a2 = *(const float4*)(obase + 2 * NN + p0);
        float4 a3 = *(const float4*)(obase + 3 * NN + p0);
        float4 b0 = *(const float4*)(obase + p1);
        float4 b1 = *(const float4*)(obase + NN + p1);
        float4 b2 = *(const float4*)(obase + 2 * NN + p1);
        float4 b3 = *(const float4*)(obase + 3 * NN + p1);
        float4 c0 = *(const float4*)(obase + p2);
        float4 c1 = *(const float4*)(obase + NN + p2);
        float4 c2 = *(const float4*)(obase + 2 * NN + p2);
        float4 c3 = *(const float4*)(obase + 3 * NN + p2);
        int4 t0 = *(const int4*)(tbase + p0);
        int4 t1 = *(const int4*)(tbase + p1);
        int4 t2 = *(const int4*)(tbase + p2);

        #define AMAX4(r0, r1, r2, r3, sh, pk) {            \
            float bv = (r0); unsigned int bc = 0;          \
            if ((r1) > bv) { bv = (r1); bc = 1; }          \
            if ((r2) > bv) { bv = (r2); bc = 2; }          \
            if ((r3) > bv) { bv = (r3); bc = 3; }          \
            pk |= bc << (sh); }
        unsigned int pk0 = 0, pk1 = 0, pk2 = 0;
        AMAX4(a0.x, a1.x, a2.x, a3.x, 0,  pk0) AMAX4(a0.y, a1.y, a2.y, a3.y, 8,  pk0)
        AMAX4(a0.z, a1.z, a2.z, a3.z, 16, pk0) AMAX4(a0.w, a1.w, a2.w, a3.w, 24, pk0)
        AMAX4(b0.x, b1.x, b2.x, b3.x, 0,  pk1) AMAX4(b0.y, b1.y, b2.y, b3.y, 8,  pk1)
        AMAX4(b0.z, b1.z, b2.z, b3.z, 16, pk1) AMAX4(b0.w, b1.w, b2.w, b3.w, 24, pk1)
        AMAX4(c0.x, c1.x, c2.x, c3.x, 0,  pk2) AMAX4(c0.y, c1.y, c2.y, c3.y, 8,  pk2)
        AMAX4(c0.z, c1.z, c2.z, c3.z, 16, pk2) AMAX4(c0.w, c1.w, c2.w, c3.w, 24, pk2)
        #undef AMAX4

        ((unsigned int*)predL)[w0] = pk0;
        ((unsigned int*)predL)[w1] = pk1;
        ((unsigned int*)tgtL)[w0] =
            (t0.x & 0xFF) | ((t0.y & 0xFF) << 8) | ((t0.z & 0xFF) << 16) | ((t0.w & 0xFF) << 24);
        ((unsigned int*)tgtL)[w1] =
            (t1.x & 0xFF) | ((t1.y & 0xFF) << 8) | ((t1.z & 0xFF) << 16) | ((t1.w & 0xFF) << 24);
        if (has2) {
            ((unsigned int*)predL)[w2] = pk2;
            ((unsigned int*)tgtL)[w2] =
                (t2.x & 0xFF) | ((t2.y & 0xFF) << 8) | ((t2.z & 0xFF) << 16) | ((t2.w & 0xFF) << 24);
        }
    }
    __syncthreads();

    // ---- P2: boundary masks, word-parallel (4 px/thread) ----
    const unsigned int* pw = (const unsigned int*)predL;
    const unsigned int* tw = (const unsigned int*)tgtL;
    for (int w = tid; w < NW; w += 1024) {
        int i = w / WPR;
        int jw = w - i * WPR;
        unsigned int mP, mT;
        #pragma unroll
        for (int s = 0; s < 2; ++s) {
            const unsigned int* src = s ? tw : pw;
            unsigned int c = src[w];
            unsigned int diff = 0;
            if (i > 0)      diff |= c ^ src[w - WPR];
            if (i < HH - 1) diff |= c ^ src[w + WPR];
            unsigned int l = (c << 8) | (jw > 0 ? (src[w - 1] >> 24) : (c & 0xFFu));
            diff |= c ^ l;
            unsigned int r = (c >> 8) | (jw < WPR - 1 ? (src[w + 1] << 24) : (c & 0xFF000000u));
            diff |= c ^ r;
            // per-byte nonzero -> 0x01
            unsigned int y = (((diff & 0x7F7F7F7Fu) + 0x7F7F7F7Fu) | diff) & 0x80808080u;
            unsigned int m01 = (y >> 7);
            if (s) mT = m01; else mP = m01;
        }
        ((unsigned int*)maskE)[w] = e ? mT : mP;
        ((unsigned int*)maskO)[w] = e ? mP : mT;
    }
    __syncthreads();   // maskE/maskO ready; predL/tgtL dead from here

    // ---- P3a: pack columns of maskE into bitmasks (3 u32 words / column) ----
    if (tid < 96 * 3) {
        int j = tid / 3, w = tid - j * 3;
        const unsigned char* colp = &maskE[w * 32 * WW + j];
        unsigned int bits = 0;
        #pragma unroll
        for (int r = 0; r < 32; ++r) bits |= ((unsigned int)colp[r * WW]) << r;
        colbits[j * 5 + w] = bits;
    }
    __syncthreads();

    // ---- P3b: column EDT via clz/ffs — ONLY this block's octant rows ----
    const int pix0 = oct * OROWS * WW;        // this block's 1152 pixels
    for (int p4 = tid; p4 < OROWS * WW; p4 += 1024) {
        int p = pix0 + p4;
        int i = p / WW;
        int j = p - i * WW;
        unsigned int w0 = colbits[j * 5 + 0];
        unsigned int w1 = colbits[j * 5 + 1];
        unsigned int hi = colbits[j * 5 + 2];
        unsigned long long lo = (unsigned long long)w0 | ((unsigned long long)w1 << 32);
        int up = 1 << 20, dn = 1 << 20;
        if (i < 64) {
            unsigned long long mu = lo & (~0ull >> (63 - i));          // rows 0..i
            if (mu) up = i - (63 - __clzll(mu));
            unsigned long long md = lo >> i;                           // rows i..63
            if (md) dn = __ffsll(md) - 1;
            else if (hi) dn = (64 - i) + (__ffs(hi) - 1);
        } else {
            int ih = i - 64;
            unsigned int mu = hi & (0xFFFFFFFFu >> (31 - ih));         // rows 64..i
            if (mu) up = ih - (31 - __clz(mu));
            else if (lo) up = i - (63 - __clzll(lo));
            unsigned int md = hi >> ih;                                // rows i..95
            if (md) dn = __ffs(md) - 1;
        }
        int d = (up < dn) ? up : dn;
        gq[p] = (d < HH) ? (float)(d * d) : BIGF;
    }
    __syncthreads();

    // ---- P4: row pass, EXACT early-exit outward scan, gated on maskO ----
    // Only masked pixels feed the max, so skip unmasked entirely.
    // best = min over o of g[j +- o] + o^2; stop once o^2 >= best.
    float m = -BIGF;
    for (int p4 = tid; p4 < OROWS * WW; p4 += 1024) {
        int p = pix0 + p4;
        if (!maskO[p]) continue;
        int i = p / WW;
        int j = p - i * WW;
        const float* grow = &gq[i * WW];
        float best = grow[j];
        for (int o = 1; o < WW; ++o) {
            float o2 = (float)(o * o);
            if (o2 >= best) break;
            int jl = j - o, jr = j + o;
            if (jl >= 0)  best = fminf(best, grow[jl] + o2);
            if (jr < WW)  best = fminf(best, grow[jr] + o2);
        }
        m = fmaxf(m, best);
    }
    // block max-reduce (16 waves)
    #pragma unroll
    for (int off = 32; off > 0; off >>= 1) m = fmaxf(m, __shfl_down(m, off));
    const int wid = tid >> 6, lid = tid & 63;
    if (lid == 0) red[wid] = m;
    __syncthreads();
    if (tid == 0) {
        float mm = red[0];
        #pragma unroll
        for (int w = 1; w < 16; ++w) mm = fmaxf(mm, red[w]);
        partial[blk] = mm;
    }
}

// ---------------------------------------------------------------------------
// K2: combine 64 partials -> mean over batches of sqrt(max(fwd,bwd,0))
// ---------------------------------------------------------------------------
__global__ void k_fin(const float* __restrict__ partial, float* __restrict__ outv) {
    if (threadIdx.x == 0) {
        float s = 0.0f;
        #pragma unroll
        for (int b = 0; b < BB; ++b) {
            float bwd = -BIGF, fwd = -BIGF;
            #pragma unroll
            for (int oo = 0; oo < 8; ++oo) {
                bwd = fmaxf(bwd, partial[b * 16 + oo]);       // e=0 octants
                fwd = fmaxf(fwd, partial[b * 16 + 8 + oo]);   // e=1 octants
            }
            s += sqrtf(fmaxf(fmaxf(fwd, bwd), 0.0f));
        }
        outv[0] = s * 0.25f;
    }
}

// ---------------------------------------------------------------------------
extern "C" void kernel_launch(void* const* d_in, const int* in_sizes, int n_in,
                              void* d_out, int out_size, void* d_ws, size_t ws_size,
                              hipStream_t stream) {
    const float* output = (const float*)d_in[0];   // [B,C,H,W] fp32
    const int* target   = (const int*)d_in[1];     // [B,H,W] int32
    float* outv         = (float*)d_out;           // scalar fp32
    float* partial      = (float*)d_ws;            // 64 floats

    k_fused<<<64, 1024, 0, stream>>>(output, target, partial);
    k_fin<<<1, 64, 0, stream>>>(partial, outv);
}